// Round 26
// baseline (290.776 us; speedup 1.0000x reference)
//
#include <hip/hip_runtime.h>
#include <stdint.h>

#define N_NODES 100000
#define N_EDGES 1000000
#define IN_F 128
#define OUT_F 128
#define NUM_RELS 64
#define NB_SCAN ((N_NODES + 255) / 256)   // 391 blocks for the scan
#define N_WAVES 16384                     // gather wave-ranges
#define GATHER_B 256                      // persistent gather blocks (1/CU)
#define GEMM_TILES ((N_NODES + 127) / 128) // 782 node tiles
#define GEMM_B (GEMM_TILES * 2)           // 1564 blocks: 128-node x 64-out
#define H16_ITEMS (N_NODES * IN_F / 8)    // 1.6M uint4s

typedef _Float16 half2v __attribute__((ext_vector_type(2)));

__device__ __forceinline__ float dot2f(uint32_t hu, uint32_t wu, float acc) {
#if __has_builtin(__builtin_amdgcn_fdot2)
    return __builtin_amdgcn_fdot2(__builtin_bit_cast(half2v, hu),
                                  __builtin_bit_cast(half2v, wu), acc, false);
#else
    half2v a = __builtin_bit_cast(half2v, hu);
    half2v b = __builtin_bit_cast(half2v, wu);
    acc = fmaf((float)a.x, (float)b.x, acc);
    acc = fmaf((float)a.y, (float)b.y, acc);
    return acc;
#endif
}

__device__ __forceinline__ uint32_t pkh2(float x, float y) {
    half2v v;
    v.x = (_Float16)x;    // RNE
    v.y = (_Float16)y;
    return __builtin_bit_cast(uint32_t, v);
}

__device__ __forceinline__ void wsw_write_one(
    const float* __restrict__ weight, uint32_t* __restrict__ wsw, int t)
{
    int r    = t >> 9;
    int p    = t & 511;
    int half = p >> 8;
    int w8   = p & 255;
    int l    = w8 >> 2;
    int ip   = w8 & 3;
    int b    = l >> 2;
    int q    = l & 3;
    int o    = 2 * q + half;
    const float* s = weight + (size_t)r * 1024 + b * 64 + (2 * ip) * 8 + o;
    half2v v;
    v.x = (_Float16)s[0];
    v.y = (_Float16)s[8];
    wsw[t] = __builtin_bit_cast(uint32_t, v);
}

__device__ __forceinline__ void h16_write_one(
    const float* __restrict__ h, uint4* __restrict__ h16_4, int t2)
{
    const float4* hp = reinterpret_cast<const float4*>(h + (size_t)t2 * 8);
    float4 a = hp[0], c = hp[1];
    uint4 r;
    r.x = pkh2(a.x, a.y);
    r.y = pkh2(a.z, a.w);
    r.z = pkh2(c.x, c.y);
    r.w = pkh2(c.z, c.w);
    h16_4[t2] = r;
}

// ---------------------------------------------------------------------------
// Merged launch (R24 proven): blocks [0, GEMM_B) -> 128-node x 64-out GEMM
// tile (acc[8][4], 56 VGPR, 1564 blocks); rest -> w-table + hist + h->fp16.
// ---------------------------------------------------------------------------
__global__ __launch_bounds__(256) void prep_gemm_fused(
    const float* __restrict__ h, const float* __restrict__ W,
    const float* __restrict__ bias, float* __restrict__ out,
    const float* __restrict__ weight, uint32_t* __restrict__ wsw,
    const int* __restrict__ dst, int* __restrict__ cnt,
    uint4* __restrict__ h16_4, int n_edges, int do_h16)
{
    if (blockIdx.x < GEMM_B) {
        const int tid  = threadIdx.x;
        const int tile = blockIdx.x >> 1;
        const int chal = blockIdx.x & 1;        // column half
        const int ty = tid >> 4, tx = tid & 15;
        const int node0 = tile * 128 + ty * 8;
        const int o0 = chal * 64 + tx * 4;

        float acc[8][4];
#pragma unroll
        for (int j = 0; j < 8; ++j)
#pragma unroll
            for (int i = 0; i < 4; ++i) acc[j][i] = 0.f;

        int nidx[8];
#pragma unroll
        for (int j = 0; j < 8; ++j) {
            int n = node0 + j;
            nidx[j] = n < N_NODES ? n : (N_NODES - 1);
        }

        for (int k = 0; k < IN_F; k += 4) {
            float hsv[8][4];
#pragma unroll
            for (int j = 0; j < 8; ++j) {
                float4 hv = *reinterpret_cast<const float4*>(h + (size_t)nidx[j] * IN_F + k);
                *reinterpret_cast<float4*>(hsv[j]) = hv;
            }
#pragma unroll
            for (int kk = 0; kk < 4; ++kk) {
                float4 wv = *reinterpret_cast<const float4*>(
                    W + (size_t)(k + kk) * OUT_F + o0);
                float wr[4];
                *reinterpret_cast<float4*>(wr) = wv;
#pragma unroll
                for (int j = 0; j < 8; ++j) {
                    const float hk = hsv[j][kk];
#pragma unroll
                    for (int i = 0; i < 4; ++i)
                        acc[j][i] = fmaf(hk, wr[i], acc[j][i]);
                }
            }
        }

        float br[4];
        *reinterpret_cast<float4*>(br) = *reinterpret_cast<const float4*>(bias + o0);

#pragma unroll
        for (int j = 0; j < 8; ++j) {
            int n = node0 + j;
            if (n < N_NODES) {
                float4 v0;
                v0.x = acc[j][0] + br[0]; v0.y = acc[j][1] + br[1];
                v0.z = acc[j][2] + br[2]; v0.w = acc[j][3] + br[3];
                *reinterpret_cast<float4*>(out + (size_t)n * OUT_F + o0) = v0;
            }
        }
        return;
    }

    // ------------------ prep block ------------------
    int t = (blockIdx.x - GEMM_B) * 256 + threadIdx.x;
    if (t < NUM_RELS * 512) {
        wsw_write_one(weight, wsw, t);
        return;
    }
    int e = t - NUM_RELS * 512;
    if (e < n_edges) {
        atomicAdd(&cnt[dst[e]], 1);
        return;
    }
    if (!do_h16) return;
    int t2 = e - n_edges;                       // 0 .. H16_ITEMS-1
    if (t2 < H16_ITEMS) h16_write_one(h, h16_4, t2);
}

__global__ __launch_bounds__(256) void block_sums(
    const int* __restrict__ cnt, int* __restrict__ part, int n)
{
    __shared__ int sdata[256];
    int i = blockIdx.x * 256 + threadIdx.x;
    sdata[threadIdx.x] = (i < n) ? cnt[i] : 0;
    __syncthreads();
    for (int s = 128; s > 0; s >>= 1) {
        if (threadIdx.x < s) sdata[threadIdx.x] += sdata[threadIdx.x + s];
        __syncthreads();
    }
    if (threadIdx.x == 0) part[blockIdx.x] = sdata[0];
}

__global__ __launch_bounds__(256) void write_off2(
    const int* __restrict__ cnt, const int* __restrict__ part,
    int* __restrict__ off, int* __restrict__ cur, int n, int n_edges)
{
    __shared__ int sdata[256];
    __shared__ int buf[256];
    const int tid = threadIdx.x;
    const int bid = blockIdx.x;

    int psum = 0;
    for (int t = tid; t < bid; t += 256) psum += part[t];
    sdata[tid] = psum;
    __syncthreads();
    for (int s = 128; s > 0; s >>= 1) {
        if (tid < s) sdata[tid] += sdata[tid + s];
        __syncthreads();
    }
    const int blockoff = sdata[0];

    int i = bid * 256 + tid;
    int v = (i < n) ? cnt[i] : 0;
    buf[tid] = v;
    __syncthreads();
    for (int ofs = 1; ofs < 256; ofs <<= 1) {
        int t = (tid >= ofs) ? buf[tid - ofs] : 0;
        __syncthreads();
        buf[tid] += t;
        __syncthreads();
    }
    int excl = buf[tid] - v + blockoff;
    if (i < n) { off[i] = excl; cur[i] = excl; }
    if (i == n - 1) off[n] = n_edges;
}

__global__ __launch_bounds__(256) void fill_and_part(
    const int* __restrict__ src, const int* __restrict__ dst,
    const int* __restrict__ rel, const float* __restrict__ norm,
    int* __restrict__ cur, int2* __restrict__ emeta,
    const int* __restrict__ off, int* __restrict__ wstart, int n_edges)
{
    int t = blockIdx.x * 256 + threadIdx.x;
    if (t < n_edges) {
        int d = dst[t];
        int p = atomicAdd(&cur[d], 1);
        int2 m;
        m.x = src[t] | (rel[t] << 20);
        m.y = __float_as_int(norm[t]);
        emeta[p] = m;
    } else {
        int w = t - n_edges;
        if (w <= N_WAVES) {
            if (w == 0) {
                wstart[0] = 0;
            } else if (w == N_WAVES) {
                wstart[N_WAVES] = N_NODES;
            } else {
                int target = (int)(((long long)N_EDGES * w) / N_WAVES);
                int lo = 0, hi = N_NODES - 1;
                while (lo < hi) {
                    int mid = (lo + hi) >> 1;
                    if (off[mid + 1] > target) hi = mid; else lo = mid + 1;
                }
                wstart[w] = lo;
            }
        } else if (w <= N_WAVES + 7) {
            int2 z; z.x = 0; z.y = 0;
            emeta[n_edges + (w - N_WAVES - 1)] = z;   // 7 zero pads
        }
    }
}

// ---------------------------------------------------------------------------
// Hot kernel v13 = v12 with `#pragma unroll 8`: removes ~7/8 of the
// pipeline-rotation moves. While-loop form re-checks the bound per body,
// so prefetch overshoot stays at +3 (pads cover it).
// ---------------------------------------------------------------------------
__global__ __launch_bounds__(1024, 4) void gather_nodes13(
    const uint4* __restrict__ h16_4, const uint32_t* __restrict__ wsw,
    const int* __restrict__ off, const int2* __restrict__ emeta,
    const int* __restrict__ wstart, float* __restrict__ out)
{
    __shared__ uint32_t wlds[NUM_RELS * 512];   // 128 KB
    {
        uint4* l4 = reinterpret_cast<uint4*>(wlds);
        const uint4* g4 = reinterpret_cast<const uint4*>(wsw);
        int t = threadIdx.x;
#pragma unroll
        for (int k = 0; k < 8; ++k)
            l4[t + k * 1024] = g4[t + k * 1024];
    }
    __syncthreads();

    const int lane = threadIdx.x & 63;
    const int wid  = threadIdx.x >> 6;
    const int b = lane >> 2;
    const int q = lane & 3;
    const uint32_t lbase = (uint32_t)(lane * 4);

    for (int wv = blockIdx.x * 16 + wid; wv < N_WAVES; wv += GATHER_B * 16) {
        const int n0 = wstart[wv];
        const int n1 = wstart[wv + 1];
        if (n0 >= n1) continue;

        int j = off[n0];
        int e_next = off[n0 + 1];

        int2 m0 = emeta[j];
        int2 m1 = emeta[j + 1];
        int2 m2 = emeta[j + 2];
        uint4 hv0 = h16_4[((uint32_t)m0.x & 0xFFFFFu) * 16 + b];
        uint4 hv1 = h16_4[((uint32_t)m1.x & 0xFFFFFu) * 16 + b];

        uint32_t base0 = ((uint32_t)m0.x >> 20) * 512 + lbase;
        uint4 wa = *reinterpret_cast<const uint4*>(&wlds[base0]);
        uint4 wb = *reinterpret_cast<const uint4*>(&wlds[base0 + 256]);

        for (int d = n0; d < n1; ++d) {
            const int idx2 = (d + 2 < n1) ? d + 2 : n1;
            const int e_nn = off[idx2];
            float a0 = 0.f, a1 = 0.f;

#pragma unroll 8
            while (j < e_next) {
                int2 m3 = emeta[j + 3];
                uint4 hv2 = h16_4[((uint32_t)m2.x & 0xFFFFFu) * 16 + b];
                uint32_t bn = ((uint32_t)m1.x >> 20) * 512 + lbase;
                uint4 wna = *reinterpret_cast<const uint4*>(&wlds[bn]);
                uint4 wnb = *reinterpret_cast<const uint4*>(&wlds[bn + 256]);

                float s0 = dot2f(hv0.x, wa.x, 0.f);
                s0 = dot2f(hv0.y, wa.y, s0);
                s0 = dot2f(hv0.z, wa.z, s0);
                s0 = dot2f(hv0.w, wa.w, s0);
                float s1 = dot2f(hv0.x, wb.x, 0.f);
                s1 = dot2f(hv0.y, wb.y, s1);
                s1 = dot2f(hv0.z, wb.z, s1);
                s1 = dot2f(hv0.w, wb.w, s1);

                const float nm = __int_as_float(m0.y);
                a0 = fmaf(s0, nm, a0);
                a1 = fmaf(s1, nm, a1);

                m0 = m1; m1 = m2; m2 = m3;
                hv0 = hv1; hv1 = hv2;
                wa = wna; wb = wnb;
                ++j;
            }

            float2* op = reinterpret_cast<float2*>(out + (size_t)d * OUT_F + b * 8 + 2 * q);
            float2 bse = *op;
            float2 res;
            res.x = fmaxf(bse.x + a0, 0.f);
            res.y = fmaxf(bse.y + a1, 0.f);
            *op = res;

            e_next = e_nn;
        }
    }
}

// ---------------------------------------------------------------------------
// Fallback hot kernel (h in f32) if ws_size can't hold h16. Same w layout.
// ---------------------------------------------------------------------------
__global__ __launch_bounds__(1024, 4) void gather_nodes6(
    const float* __restrict__ h, const uint32_t* __restrict__ wsw,
    const int* __restrict__ off, const int2* __restrict__ emeta,
    const int* __restrict__ wstart, float* __restrict__ out)
{
    __shared__ uint32_t wlds[NUM_RELS * 512];   // 128 KB
    {
        uint4* l4 = reinterpret_cast<uint4*>(wlds);
        const uint4* g4 = reinterpret_cast<const uint4*>(wsw);
        int t = threadIdx.x;
#pragma unroll
        for (int k = 0; k < 8; ++k)
            l4[t + k * 1024] = g4[t + k * 1024];
    }
    __syncthreads();

    const int lane = threadIdx.x & 63;
    const int wid  = threadIdx.x >> 6;
    const int b = lane >> 2;
    const int q = lane & 3;
    const uint32_t lbase = (uint32_t)(lane * 4);

    for (int wv = blockIdx.x * 16 + wid; wv < N_WAVES; wv += GATHER_B * 16) {
        const int n0 = wstart[wv];
        const int n1 = wstart[wv + 1];
        if (n0 >= n1) continue;

        int j = off[n0];
        int2 m0 = emeta[j];
        int2 m1 = emeta[j + 1];
        int2 m2 = emeta[j + 2];

        const float4* hr0 = reinterpret_cast<const float4*>(
            h + (size_t)((uint32_t)m0.x & 0xFFFFFu) * IN_F + b * 8);
        float4 h0A = hr0[0], h0B = hr0[1];
        const float4* hr1 = reinterpret_cast<const float4*>(
            h + (size_t)((uint32_t)m1.x & 0xFFFFFu) * IN_F + b * 8);
        float4 h1A = hr1[0], h1B = hr1[1];

        uint32_t base0 = ((uint32_t)m0.x >> 20) * 512 + lbase;
        uint4 wa = *reinterpret_cast<const uint4*>(&wlds[base0]);
        uint4 wb = *reinterpret_cast<const uint4*>(&wlds[base0 + 256]);

        for (int d = n0; d < n1; ++d) {
            const int end_d = off[d + 1];
            float a0 = 0.f, a1 = 0.f;

            while (j < end_d) {
                int2 m3 = emeta[j + 3];
                const float4* hr2 = reinterpret_cast<const float4*>(
                    h + (size_t)((uint32_t)m2.x & 0xFFFFFu) * IN_F + b * 8);
                float4 h2A = hr2[0], h2B = hr2[1];
                uint32_t bn = ((uint32_t)m1.x >> 20) * 512 + lbase;
                uint4 wna = *reinterpret_cast<const uint4*>(&wlds[bn]);
                uint4 wnb = *reinterpret_cast<const uint4*>(&wlds[bn + 256]);

                uint32_t h01 = __builtin_bit_cast(uint32_t, __builtin_amdgcn_cvt_pkrtz(h0A.x, h0A.y));
                uint32_t h23 = __builtin_bit_cast(uint32_t, __builtin_amdgcn_cvt_pkrtz(h0A.z, h0A.w));
                uint32_t h45 = __builtin_bit_cast(uint32_t, __builtin_amdgcn_cvt_pkrtz(h0B.x, h0B.y));
                uint32_t h67 = __builtin_bit_cast(uint32_t, __builtin_amdgcn_cvt_pkrtz(h0B.z, h0B.w));

                float s0 = dot2f(h01, wa.x, 0.f);
                s0 = dot2f(h23, wa.y, s0);
                s0 = dot2f(h45, wa.z, s0);
                s0 = dot2f(h67, wa.w, s0);
                float s1 = dot2f(h01, wb.x, 0.f);
                s1 = dot2f(h23, wb.y, s1);
                s1 = dot2f(h45, wb.z, s1);
                s1 = dot2f(h67, wb.w, s1);

                const float nm = __int_as_float(m0.y);
                a0 = fmaf(s0, nm, a0);
                a1 = fmaf(s1, nm, a1);

                m0 = m1; m1 = m2; m2 = m3;
                h0A = h1A; h0B = h1B; h1A = h2A; h1B = h2B;
                wa = wna; wb = wnb;
                ++j;
            }

            float2* op = reinterpret_cast<float2*>(out + (size_t)d * OUT_F + b * 8 + 2 * q);
            float2 bse = *op;
            float2 res;
            res.x = fmaxf(bse.x + a0, 0.f);
            res.y = fmaxf(bse.y + a1, 0.f);
            *op = res;
        }
    }
}

extern "C" void kernel_launch(void* const* d_in, const int* in_sizes, int n_in,
                              void* d_out, int out_size, void* d_ws, size_t ws_size,
                              hipStream_t stream)
{
    const float* h      = (const float*)d_in[0];
    const float* norm   = (const float*)d_in[1];
    const float* weight = (const float*)d_in[2];
    const float* loop_w = (const float*)d_in[3];
    const float* bias   = (const float*)d_in[4];
    const int*   src    = (const int*)d_in[5];
    const int*   dst    = (const int*)d_in[6];
    const int*   rel    = (const int*)d_in[7];
    float* out = (float*)d_out;

    // ws layout: cnt[N], off[N+1], cur[N], part[512], wstart[N_WAVES+1],
    // wsw[64*512 u32], emeta[E+7] int2, h16[N*IN_F] fp16  -> ~35 MB
    char* wsb = (char*)d_ws;
    char* ws0 = wsb;
    int*  cnt    = (int*)wsb;  wsb += sizeof(int) * N_NODES;
    int*  off    = (int*)wsb;  wsb += sizeof(int) * (N_NODES + 1);
    int*  cur    = (int*)wsb;  wsb += sizeof(int) * N_NODES;
    int*  part   = (int*)wsb;  wsb += sizeof(int) * 512;
    int*  wstart = (int*)wsb;  wsb += sizeof(int) * (N_WAVES + 1);
    wsb = (char*)(((uintptr_t)wsb + 15) & ~(uintptr_t)15);
    uint32_t* wsw = (uint32_t*)wsb; wsb += sizeof(uint32_t) * NUM_RELS * 512;
    int2* emeta = (int2*)wsb;  wsb += sizeof(int2) * (N_EDGES + 7);
    wsb = (char*)(((uintptr_t)wsb + 15) & ~(uintptr_t)15);
    uint4* h16_4 = (uint4*)wsb; wsb += (size_t)N_NODES * IN_F * 2;

    const int use_h16 = (size_t)(wsb - ws0) <= ws_size;   // host-constant

    hipMemsetAsync(cnt, 0, sizeof(int) * N_NODES, stream);

    const int h16_threads = use_h16 ? H16_ITEMS : 0;
    const int prep_blocks = (NUM_RELS * 512 + N_EDGES + h16_threads + 255) / 256;
    prep_gemm_fused<<<GEMM_B + prep_blocks, 256, 0, stream>>>(
        h, loop_w, bias, out, weight, wsw, dst, cnt, h16_4, N_EDGES, use_h16);
    block_sums<<<NB_SCAN, 256, 0, stream>>>(cnt, part, N_NODES);
    write_off2<<<NB_SCAN, 256, 0, stream>>>(cnt, part, off, cur, N_NODES, N_EDGES);
    const int fp_grid = (N_EDGES + N_WAVES + 8 + 255) / 256;
    fill_and_part<<<fp_grid, 256, 0, stream>>>(src, dst, rel, norm, cur, emeta,
                                               off, wstart, N_EDGES);

    if (use_h16) {
        gather_nodes13<<<GATHER_B, 1024, 0, stream>>>(h16_4, wsw, off, emeta, wstart, out);
    } else {
        gather_nodes6<<<GATHER_B, 1024, 0, stream>>>(h, wsw, off, emeta, wstart, out);
    }
}

// Round 27
// 274.450 us; speedup vs baseline: 1.0595x; 1.0595x over previous
//
#include <hip/hip_runtime.h>
#include <stdint.h>

#define N_NODES 100000
#define N_EDGES 1000000
#define IN_F 128
#define OUT_F 128
#define NUM_RELS 64
#define NB_SCAN ((N_NODES + 255) / 256)   // 391 blocks for the scan
#define N_WAVES 16384                     // gather wave-ranges
#define GATHER_B 256                      // persistent gather blocks (1/CU)
#define GEMM_TILES ((N_NODES + 127) / 128) // 782 node tiles
#define GEMM_B (GEMM_TILES * 2)           // 1564 blocks: 128-node x 64-out
#define H16_ITEMS (N_NODES * IN_F / 8)    // 1.6M uint4s

typedef _Float16 half2v __attribute__((ext_vector_type(2)));

__device__ __forceinline__ float dot2f(uint32_t hu, uint32_t wu, float acc) {
#if __has_builtin(__builtin_amdgcn_fdot2)
    return __builtin_amdgcn_fdot2(__builtin_bit_cast(half2v, hu),
                                  __builtin_bit_cast(half2v, wu), acc, false);
#else
    half2v a = __builtin_bit_cast(half2v, hu);
    half2v b = __builtin_bit_cast(half2v, wu);
    acc = fmaf((float)a.x, (float)b.x, acc);
    acc = fmaf((float)a.y, (float)b.y, acc);
    return acc;
#endif
}

__device__ __forceinline__ uint32_t pkh2(float x, float y) {
    half2v v;
    v.x = (_Float16)x;    // RNE
    v.y = (_Float16)y;
    return __builtin_bit_cast(uint32_t, v);
}

__device__ __forceinline__ void wsw_write_one(
    const float* __restrict__ weight, uint32_t* __restrict__ wsw, int t)
{
    int r    = t >> 9;
    int p    = t & 511;
    int half = p >> 8;
    int w8   = p & 255;
    int l    = w8 >> 2;
    int ip   = w8 & 3;
    int b    = l >> 2;
    int q    = l & 3;
    int o    = 2 * q + half;
    const float* s = weight + (size_t)r * 1024 + b * 64 + (2 * ip) * 8 + o;
    half2v v;
    v.x = (_Float16)s[0];
    v.y = (_Float16)s[8];
    wsw[t] = __builtin_bit_cast(uint32_t, v);
}

__device__ __forceinline__ void h16_write_one(
    const float* __restrict__ h, uint4* __restrict__ h16_4, int t2)
{
    const float4* hp = reinterpret_cast<const float4*>(h + (size_t)t2 * 8);
    float4 a = hp[0], c = hp[1];
    uint4 r;
    r.x = pkh2(a.x, a.y);
    r.y = pkh2(a.z, a.w);
    r.z = pkh2(c.x, c.y);
    r.w = pkh2(c.z, c.w);
    h16_4[t2] = r;
}

// ---------------------------------------------------------------------------
// Merged launch (R24 proven): blocks [0, GEMM_B) -> 128-node x 64-out GEMM
// tile (acc[8][4], 56 VGPR, 1564 blocks); rest -> w-table + hist + h->fp16.
// ---------------------------------------------------------------------------
__global__ __launch_bounds__(256) void prep_gemm_fused(
    const float* __restrict__ h, const float* __restrict__ W,
    const float* __restrict__ bias, float* __restrict__ out,
    const float* __restrict__ weight, uint32_t* __restrict__ wsw,
    const int* __restrict__ dst, int* __restrict__ cnt,
    uint4* __restrict__ h16_4, int n_edges, int do_h16)
{
    if (blockIdx.x < GEMM_B) {
        const int tid  = threadIdx.x;
        const int tile = blockIdx.x >> 1;
        const int chal = blockIdx.x & 1;        // column half
        const int ty = tid >> 4, tx = tid & 15;
        const int node0 = tile * 128 + ty * 8;
        const int o0 = chal * 64 + tx * 4;

        float acc[8][4];
#pragma unroll
        for (int j = 0; j < 8; ++j)
#pragma unroll
            for (int i = 0; i < 4; ++i) acc[j][i] = 0.f;

        int nidx[8];
#pragma unroll
        for (int j = 0; j < 8; ++j) {
            int n = node0 + j;
            nidx[j] = n < N_NODES ? n : (N_NODES - 1);
        }

        for (int k = 0; k < IN_F; k += 4) {
            float hsv[8][4];
#pragma unroll
            for (int j = 0; j < 8; ++j) {
                float4 hv = *reinterpret_cast<const float4*>(h + (size_t)nidx[j] * IN_F + k);
                *reinterpret_cast<float4*>(hsv[j]) = hv;
            }
#pragma unroll
            for (int kk = 0; kk < 4; ++kk) {
                float4 wv = *reinterpret_cast<const float4*>(
                    W + (size_t)(k + kk) * OUT_F + o0);
                float wr[4];
                *reinterpret_cast<float4*>(wr) = wv;
#pragma unroll
                for (int j = 0; j < 8; ++j) {
                    const float hk = hsv[j][kk];
#pragma unroll
                    for (int i = 0; i < 4; ++i)
                        acc[j][i] = fmaf(hk, wr[i], acc[j][i]);
                }
            }
        }

        float br[4];
        *reinterpret_cast<float4*>(br) = *reinterpret_cast<const float4*>(bias + o0);

#pragma unroll
        for (int j = 0; j < 8; ++j) {
            int n = node0 + j;
            if (n < N_NODES) {
                float4 v0;
                v0.x = acc[j][0] + br[0]; v0.y = acc[j][1] + br[1];
                v0.z = acc[j][2] + br[2]; v0.w = acc[j][3] + br[3];
                *reinterpret_cast<float4*>(out + (size_t)n * OUT_F + o0) = v0;
            }
        }
        return;
    }

    // ------------------ prep block ------------------
    int t = (blockIdx.x - GEMM_B) * 256 + threadIdx.x;
    if (t < NUM_RELS * 512) {
        wsw_write_one(weight, wsw, t);
        return;
    }
    int e = t - NUM_RELS * 512;
    if (e < n_edges) {
        atomicAdd(&cnt[dst[e]], 1);
        return;
    }
    if (!do_h16) return;
    int t2 = e - n_edges;                       // 0 .. H16_ITEMS-1
    if (t2 < H16_ITEMS) h16_write_one(h, h16_4, t2);
}

__global__ __launch_bounds__(256) void block_sums(
    const int* __restrict__ cnt, int* __restrict__ part, int n)
{
    __shared__ int sdata[256];
    int i = blockIdx.x * 256 + threadIdx.x;
    sdata[threadIdx.x] = (i < n) ? cnt[i] : 0;
    __syncthreads();
    for (int s = 128; s > 0; s >>= 1) {
        if (threadIdx.x < s) sdata[threadIdx.x] += sdata[threadIdx.x + s];
        __syncthreads();
    }
    if (threadIdx.x == 0) part[blockIdx.x] = sdata[0];
}

__global__ __launch_bounds__(256) void write_off2(
    const int* __restrict__ cnt, const int* __restrict__ part,
    int* __restrict__ off, int* __restrict__ cur, int n, int n_edges)
{
    __shared__ int sdata[256];
    __shared__ int buf[256];
    const int tid = threadIdx.x;
    const int bid = blockIdx.x;

    int psum = 0;
    for (int t = tid; t < bid; t += 256) psum += part[t];
    sdata[tid] = psum;
    __syncthreads();
    for (int s = 128; s > 0; s >>= 1) {
        if (tid < s) sdata[tid] += sdata[tid + s];
        __syncthreads();
    }
    const int blockoff = sdata[0];

    int i = bid * 256 + tid;
    int v = (i < n) ? cnt[i] : 0;
    buf[tid] = v;
    __syncthreads();
    for (int ofs = 1; ofs < 256; ofs <<= 1) {
        int t = (tid >= ofs) ? buf[tid - ofs] : 0;
        __syncthreads();
        buf[tid] += t;
        __syncthreads();
    }
    int excl = buf[tid] - v + blockoff;
    if (i < n) { off[i] = excl; cur[i] = excl; }
    if (i == n - 1) off[n] = n_edges;
}

__global__ __launch_bounds__(256) void fill_and_part(
    const int* __restrict__ src, const int* __restrict__ dst,
    const int* __restrict__ rel, const float* __restrict__ norm,
    int* __restrict__ cur, int2* __restrict__ emeta,
    const int* __restrict__ off, int* __restrict__ wstart, int n_edges)
{
    int t = blockIdx.x * 256 + threadIdx.x;
    if (t < n_edges) {
        int d = dst[t];
        int p = atomicAdd(&cur[d], 1);
        int2 m;
        m.x = src[t] | (rel[t] << 20);
        m.y = __float_as_int(norm[t]);
        emeta[p] = m;
    } else {
        int w = t - n_edges;
        if (w <= N_WAVES) {
            if (w == 0) {
                wstart[0] = 0;
            } else if (w == N_WAVES) {
                wstart[N_WAVES] = N_NODES;
            } else {
                int target = (int)(((long long)N_EDGES * w) / N_WAVES);
                int lo = 0, hi = N_NODES - 1;
                while (lo < hi) {
                    int mid = (lo + hi) >> 1;
                    if (off[mid + 1] > target) hi = mid; else lo = mid + 1;
                }
                wstart[w] = lo;
            }
        } else if (w <= N_WAVES + 7) {
            int2 z; z.x = 0; z.y = 0;
            emeta[n_edges + (w - N_WAVES - 1)] = z;   // 7 zero pads
        }
    }
}

// ---------------------------------------------------------------------------
// Hot kernel v12 (R25 proven best): fp16 table in LDS, persistent 256 blocks,
// inner edge loop `#pragma unroll 4` (removes ~3/4 of pipeline-rotation
// moves; unroll 8 measured worse — register/I-cache cost exceeds savings).
// Per edge: 1 meta + 1 uint4 h16 load + 2 ds_read_b128 + 8 fdot2 + 2 fma.
// ---------------------------------------------------------------------------
__global__ __launch_bounds__(1024, 4) void gather_nodes12(
    const uint4* __restrict__ h16_4, const uint32_t* __restrict__ wsw,
    const int* __restrict__ off, const int2* __restrict__ emeta,
    const int* __restrict__ wstart, float* __restrict__ out)
{
    __shared__ uint32_t wlds[NUM_RELS * 512];   // 128 KB
    {
        uint4* l4 = reinterpret_cast<uint4*>(wlds);
        const uint4* g4 = reinterpret_cast<const uint4*>(wsw);
        int t = threadIdx.x;
#pragma unroll
        for (int k = 0; k < 8; ++k)
            l4[t + k * 1024] = g4[t + k * 1024];
    }
    __syncthreads();

    const int lane = threadIdx.x & 63;
    const int wid  = threadIdx.x >> 6;
    const int b = lane >> 2;
    const int q = lane & 3;
    const uint32_t lbase = (uint32_t)(lane * 4);

    for (int wv = blockIdx.x * 16 + wid; wv < N_WAVES; wv += GATHER_B * 16) {
        const int n0 = wstart[wv];
        const int n1 = wstart[wv + 1];
        if (n0 >= n1) continue;

        int j = off[n0];
        int e_next = off[n0 + 1];

        int2 m0 = emeta[j];
        int2 m1 = emeta[j + 1];
        int2 m2 = emeta[j + 2];
        uint4 hv0 = h16_4[((uint32_t)m0.x & 0xFFFFFu) * 16 + b];
        uint4 hv1 = h16_4[((uint32_t)m1.x & 0xFFFFFu) * 16 + b];

        uint32_t base0 = ((uint32_t)m0.x >> 20) * 512 + lbase;
        uint4 wa = *reinterpret_cast<const uint4*>(&wlds[base0]);
        uint4 wb = *reinterpret_cast<const uint4*>(&wlds[base0 + 256]);

        for (int d = n0; d < n1; ++d) {
            const int idx2 = (d + 2 < n1) ? d + 2 : n1;
            const int e_nn = off[idx2];
            float a0 = 0.f, a1 = 0.f;

#pragma unroll 4
            while (j < e_next) {
                int2 m3 = emeta[j + 3];
                uint4 hv2 = h16_4[((uint32_t)m2.x & 0xFFFFFu) * 16 + b];
                uint32_t bn = ((uint32_t)m1.x >> 20) * 512 + lbase;
                uint4 wna = *reinterpret_cast<const uint4*>(&wlds[bn]);
                uint4 wnb = *reinterpret_cast<const uint4*>(&wlds[bn + 256]);

                float s0 = dot2f(hv0.x, wa.x, 0.f);
                s0 = dot2f(hv0.y, wa.y, s0);
                s0 = dot2f(hv0.z, wa.z, s0);
                s0 = dot2f(hv0.w, wa.w, s0);
                float s1 = dot2f(hv0.x, wb.x, 0.f);
                s1 = dot2f(hv0.y, wb.y, s1);
                s1 = dot2f(hv0.z, wb.z, s1);
                s1 = dot2f(hv0.w, wb.w, s1);

                const float nm = __int_as_float(m0.y);
                a0 = fmaf(s0, nm, a0);
                a1 = fmaf(s1, nm, a1);

                m0 = m1; m1 = m2; m2 = m3;
                hv0 = hv1; hv1 = hv2;
                wa = wna; wb = wnb;
                ++j;
            }

            float2* op = reinterpret_cast<float2*>(out + (size_t)d * OUT_F + b * 8 + 2 * q);
            float2 bse = *op;
            float2 res;
            res.x = fmaxf(bse.x + a0, 0.f);
            res.y = fmaxf(bse.y + a1, 0.f);
            *op = res;

            e_next = e_nn;
        }
    }
}

// ---------------------------------------------------------------------------
// Fallback hot kernel (h in f32) if ws_size can't hold h16. Same w layout.
// ---------------------------------------------------------------------------
__global__ __launch_bounds__(1024, 4) void gather_nodes6(
    const float* __restrict__ h, const uint32_t* __restrict__ wsw,
    const int* __restrict__ off, const int2* __restrict__ emeta,
    const int* __restrict__ wstart, float* __restrict__ out)
{
    __shared__ uint32_t wlds[NUM_RELS * 512];   // 128 KB
    {
        uint4* l4 = reinterpret_cast<uint4*>(wlds);
        const uint4* g4 = reinterpret_cast<const uint4*>(wsw);
        int t = threadIdx.x;
#pragma unroll
        for (int k = 0; k < 8; ++k)
            l4[t + k * 1024] = g4[t + k * 1024];
    }
    __syncthreads();

    const int lane = threadIdx.x & 63;
    const int wid  = threadIdx.x >> 6;
    const int b = lane >> 2;
    const int q = lane & 3;
    const uint32_t lbase = (uint32_t)(lane * 4);

    for (int wv = blockIdx.x * 16 + wid; wv < N_WAVES; wv += GATHER_B * 16) {
        const int n0 = wstart[wv];
        const int n1 = wstart[wv + 1];
        if (n0 >= n1) continue;

        int j = off[n0];
        int2 m0 = emeta[j];
        int2 m1 = emeta[j + 1];
        int2 m2 = emeta[j + 2];

        const float4* hr0 = reinterpret_cast<const float4*>(
            h + (size_t)((uint32_t)m0.x & 0xFFFFFu) * IN_F + b * 8);
        float4 h0A = hr0[0], h0B = hr0[1];
        const float4* hr1 = reinterpret_cast<const float4*>(
            h + (size_t)((uint32_t)m1.x & 0xFFFFFu) * IN_F + b * 8);
        float4 h1A = hr1[0], h1B = hr1[1];

        uint32_t base0 = ((uint32_t)m0.x >> 20) * 512 + lbase;
        uint4 wa = *reinterpret_cast<const uint4*>(&wlds[base0]);
        uint4 wb = *reinterpret_cast<const uint4*>(&wlds[base0 + 256]);

        for (int d = n0; d < n1; ++d) {
            const int end_d = off[d + 1];
            float a0 = 0.f, a1 = 0.f;

            while (j < end_d) {
                int2 m3 = emeta[j + 3];
                const float4* hr2 = reinterpret_cast<const float4*>(
                    h + (size_t)((uint32_t)m2.x & 0xFFFFFu) * IN_F + b * 8);
                float4 h2A = hr2[0], h2B = hr2[1];
                uint32_t bn = ((uint32_t)m1.x >> 20) * 512 + lbase;
                uint4 wna = *reinterpret_cast<const uint4*>(&wlds[bn]);
                uint4 wnb = *reinterpret_cast<const uint4*>(&wlds[bn + 256]);

                uint32_t h01 = __builtin_bit_cast(uint32_t, __builtin_amdgcn_cvt_pkrtz(h0A.x, h0A.y));
                uint32_t h23 = __builtin_bit_cast(uint32_t, __builtin_amdgcn_cvt_pkrtz(h0A.z, h0A.w));
                uint32_t h45 = __builtin_bit_cast(uint32_t, __builtin_amdgcn_cvt_pkrtz(h0B.x, h0B.y));
                uint32_t h67 = __builtin_bit_cast(uint32_t, __builtin_amdgcn_cvt_pkrtz(h0B.z, h0B.w));

                float s0 = dot2f(h01, wa.x, 0.f);
                s0 = dot2f(h23, wa.y, s0);
                s0 = dot2f(h45, wa.z, s0);
                s0 = dot2f(h67, wa.w, s0);
                float s1 = dot2f(h01, wb.x, 0.f);
                s1 = dot2f(h23, wb.y, s1);
                s1 = dot2f(h45, wb.z, s1);
                s1 = dot2f(h67, wb.w, s1);

                const float nm = __int_as_float(m0.y);
                a0 = fmaf(s0, nm, a0);
                a1 = fmaf(s1, nm, a1);

                m0 = m1; m1 = m2; m2 = m3;
                h0A = h1A; h0B = h1B; h1A = h2A; h1B = h2B;
                wa = wna; wb = wnb;
                ++j;
            }

            float2* op = reinterpret_cast<float2*>(out + (size_t)d * OUT_F + b * 8 + 2 * q);
            float2 bse = *op;
            float2 res;
            res.x = fmaxf(bse.x + a0, 0.f);
            res.y = fmaxf(bse.y + a1, 0.f);
            *op = res;
        }
    }
}

extern "C" void kernel_launch(void* const* d_in, const int* in_sizes, int n_in,
                              void* d_out, int out_size, void* d_ws, size_t ws_size,
                              hipStream_t stream)
{
    const float* h      = (const float*)d_in[0];
    const float* norm   = (const float*)d_in[1];
    const float* weight = (const float*)d_in[2];
    const float* loop_w = (const float*)d_in[3];
    const float* bias   = (const float*)d_in[4];
    const int*   src    = (const int*)d_in[5];
    const int*   dst    = (const int*)d_in[6];
    const int*   rel    = (const int*)d_in[7];
    float* out = (float*)d_out;

    // ws layout: cnt[N], off[N+1], cur[N], part[512], wstart[N_WAVES+1],
    // wsw[64*512 u32], emeta[E+7] int2, h16[N*IN_F] fp16  -> ~35 MB
    char* wsb = (char*)d_ws;
    char* ws0 = wsb;
    int*  cnt    = (int*)wsb;  wsb += sizeof(int) * N_NODES;
    int*  off    = (int*)wsb;  wsb += sizeof(int) * (N_NODES + 1);
    int*  cur    = (int*)wsb;  wsb += sizeof(int) * N_NODES;
    int*  part   = (int*)wsb;  wsb += sizeof(int) * 512;
    int*  wstart = (int*)wsb;  wsb += sizeof(int) * (N_WAVES + 1);
    wsb = (char*)(((uintptr_t)wsb + 15) & ~(uintptr_t)15);
    uint32_t* wsw = (uint32_t*)wsb; wsb += sizeof(uint32_t) * NUM_RELS * 512;
    int2* emeta = (int2*)wsb;  wsb += sizeof(int2) * (N_EDGES + 7);
    wsb = (char*)(((uintptr_t)wsb + 15) & ~(uintptr_t)15);
    uint4* h16_4 = (uint4*)wsb; wsb += (size_t)N_NODES * IN_F * 2;

    const int use_h16 = (size_t)(wsb - ws0) <= ws_size;   // host-constant

    hipMemsetAsync(cnt, 0, sizeof(int) * N_NODES, stream);

    const int h16_threads = use_h16 ? H16_ITEMS : 0;
    const int prep_blocks = (NUM_RELS * 512 + N_EDGES + h16_threads + 255) / 256;
    prep_gemm_fused<<<GEMM_B + prep_blocks, 256, 0, stream>>>(
        h, loop_w, bias, out, weight, wsw, dst, cnt, h16_4, N_EDGES, use_h16);
    block_sums<<<NB_SCAN, 256, 0, stream>>>(cnt, part, N_NODES);
    write_off2<<<NB_SCAN, 256, 0, stream>>>(cnt, part, off, cur, N_NODES, N_EDGES);
    const int fp_grid = (N_EDGES + N_WAVES + 8 + 255) / 256;
    fill_and_part<<<fp_grid, 256, 0, stream>>>(src, dst, rel, norm, cur, emeta,
                                               off, wstart, N_EDGES);

    if (use_h16) {
        gather_nodes12<<<GATHER_B, 1024, 0, stream>>>(h16_4, wsw, off, emeta, wstart, out);
    } else {
        gather_nodes6<<<GATHER_B, 1024, 0, stream>>>(h, wsw, off, emeta, wstart, out);
    }
}

// Round 28
// 271.732 us; speedup vs baseline: 1.0701x; 1.0100x over previous
//
#include <hip/hip_runtime.h>
#include <stdint.h>

#define N_NODES 100000
#define N_EDGES 1000000
#define IN_F 128
#define OUT_F 128
#define NUM_RELS 64
#define NB_SCAN ((N_NODES + 255) / 256)   // 391 blocks for the scan
#define N_WAVES 16384                     // gather wave-ranges
#define GATHER_B 256                      // persistent gather blocks (1/CU)
#define GEMM_TILES ((N_NODES + 127) / 128) // 782 node tiles
#define GEMM_B (GEMM_TILES * 2)           // 1564 blocks: 128-node x 64-out
#define H16_ITEMS (N_NODES * IN_F / 8)    // 1.6M uint4s

typedef _Float16 half2v __attribute__((ext_vector_type(2)));

__device__ __forceinline__ float dot2f(uint32_t hu, uint32_t wu, float acc) {
#if __has_builtin(__builtin_amdgcn_fdot2)
    return __builtin_amdgcn_fdot2(__builtin_bit_cast(half2v, hu),
                                  __builtin_bit_cast(half2v, wu), acc, false);
#else
    half2v a = __builtin_bit_cast(half2v, hu);
    half2v b = __builtin_bit_cast(half2v, wu);
    acc = fmaf((float)a.x, (float)b.x, acc);
    acc = fmaf((float)a.y, (float)b.y, acc);
    return acc;
#endif
}

__device__ __forceinline__ uint32_t pkh2(float x, float y) {
    half2v v;
    v.x = (_Float16)x;    // RNE
    v.y = (_Float16)y;
    return __builtin_bit_cast(uint32_t, v);
}

__device__ __forceinline__ void wsw_write_one(
    const float* __restrict__ weight, uint32_t* __restrict__ wsw, int t)
{
    int r    = t >> 9;
    int p    = t & 511;
    int half = p >> 8;
    int w8   = p & 255;
    int l    = w8 >> 2;
    int ip   = w8 & 3;
    int b    = l >> 2;
    int q    = l & 3;
    int o    = 2 * q + half;
    const float* s = weight + (size_t)r * 1024 + b * 64 + (2 * ip) * 8 + o;
    half2v v;
    v.x = (_Float16)s[0];
    v.y = (_Float16)s[8];
    wsw[t] = __builtin_bit_cast(uint32_t, v);
}

__device__ __forceinline__ void h16_write_one(
    const float* __restrict__ h, uint4* __restrict__ h16_4, int t2)
{
    const float4* hp = reinterpret_cast<const float4*>(h + (size_t)t2 * 8);
    float4 a = hp[0], c = hp[1];
    uint4 r;
    r.x = pkh2(a.x, a.y);
    r.y = pkh2(a.z, a.w);
    r.z = pkh2(c.x, c.y);
    r.w = pkh2(c.z, c.w);
    h16_4[t2] = r;
}

// ---------------------------------------------------------------------------
// Merged launch (R24 proven): blocks [0, GEMM_B) -> 128-node x 64-out GEMM
// tile (acc[8][4], 1564 blocks); k-loop `#pragma unroll 2` doubles loads in
// flight (latency-bound phase, VGPR headroom 56->~80). Rest of blocks ->
// w-table + hist + h->fp16.
// ---------------------------------------------------------------------------
__global__ __launch_bounds__(256) void prep_gemm_fused(
    const float* __restrict__ h, const float* __restrict__ W,
    const float* __restrict__ bias, float* __restrict__ out,
    const float* __restrict__ weight, uint32_t* __restrict__ wsw,
    const int* __restrict__ dst, int* __restrict__ cnt,
    uint4* __restrict__ h16_4, int n_edges, int do_h16)
{
    if (blockIdx.x < GEMM_B) {
        const int tid  = threadIdx.x;
        const int tile = blockIdx.x >> 1;
        const int chal = blockIdx.x & 1;        // column half
        const int ty = tid >> 4, tx = tid & 15;
        const int node0 = tile * 128 + ty * 8;
        const int o0 = chal * 64 + tx * 4;

        float acc[8][4];
#pragma unroll
        for (int j = 0; j < 8; ++j)
#pragma unroll
            for (int i = 0; i < 4; ++i) acc[j][i] = 0.f;

        int nidx[8];
#pragma unroll
        for (int j = 0; j < 8; ++j) {
            int n = node0 + j;
            nidx[j] = n < N_NODES ? n : (N_NODES - 1);
        }

#pragma unroll 2
        for (int k = 0; k < IN_F; k += 4) {
            float hsv[8][4];
#pragma unroll
            for (int j = 0; j < 8; ++j) {
                float4 hv = *reinterpret_cast<const float4*>(h + (size_t)nidx[j] * IN_F + k);
                *reinterpret_cast<float4*>(hsv[j]) = hv;
            }
#pragma unroll
            for (int kk = 0; kk < 4; ++kk) {
                float4 wv = *reinterpret_cast<const float4*>(
                    W + (size_t)(k + kk) * OUT_F + o0);
                float wr[4];
                *reinterpret_cast<float4*>(wr) = wv;
#pragma unroll
                for (int j = 0; j < 8; ++j) {
                    const float hk = hsv[j][kk];
#pragma unroll
                    for (int i = 0; i < 4; ++i)
                        acc[j][i] = fmaf(hk, wr[i], acc[j][i]);
                }
            }
        }

        float br[4];
        *reinterpret_cast<float4*>(br) = *reinterpret_cast<const float4*>(bias + o0);

#pragma unroll
        for (int j = 0; j < 8; ++j) {
            int n = node0 + j;
            if (n < N_NODES) {
                float4 v0;
                v0.x = acc[j][0] + br[0]; v0.y = acc[j][1] + br[1];
                v0.z = acc[j][2] + br[2]; v0.w = acc[j][3] + br[3];
                *reinterpret_cast<float4*>(out + (size_t)n * OUT_F + o0) = v0;
            }
        }
        return;
    }

    // ------------------ prep block ------------------
    int t = (blockIdx.x - GEMM_B) * 256 + threadIdx.x;
    if (t < NUM_RELS * 512) {
        wsw_write_one(weight, wsw, t);
        return;
    }
    int e = t - NUM_RELS * 512;
    if (e < n_edges) {
        atomicAdd(&cnt[dst[e]], 1);
        return;
    }
    if (!do_h16) return;
    int t2 = e - n_edges;                       // 0 .. H16_ITEMS-1
    if (t2 < H16_ITEMS) h16_write_one(h, h16_4, t2);
}

__global__ __launch_bounds__(256) void block_sums(
    const int* __restrict__ cnt, int* __restrict__ part, int n)
{
    __shared__ int sdata[256];
    int i = blockIdx.x * 256 + threadIdx.x;
    sdata[threadIdx.x] = (i < n) ? cnt[i] : 0;
    __syncthreads();
    for (int s = 128; s > 0; s >>= 1) {
        if (threadIdx.x < s) sdata[threadIdx.x] += sdata[threadIdx.x + s];
        __syncthreads();
    }
    if (threadIdx.x == 0) part[blockIdx.x] = sdata[0];
}

__global__ __launch_bounds__(256) void write_off2(
    const int* __restrict__ cnt, const int* __restrict__ part,
    int* __restrict__ off, int* __restrict__ cur, int n, int n_edges)
{
    __shared__ int sdata[256];
    __shared__ int buf[256];
    const int tid = threadIdx.x;
    const int bid = blockIdx.x;

    int psum = 0;
    for (int t = tid; t < bid; t += 256) psum += part[t];
    sdata[tid] = psum;
    __syncthreads();
    for (int s = 128; s > 0; s >>= 1) {
        if (tid < s) sdata[tid] += sdata[tid + s];
        __syncthreads();
    }
    const int blockoff = sdata[0];

    int i = bid * 256 + tid;
    int v = (i < n) ? cnt[i] : 0;
    buf[tid] = v;
    __syncthreads();
    for (int ofs = 1; ofs < 256; ofs <<= 1) {
        int t = (tid >= ofs) ? buf[tid - ofs] : 0;
        __syncthreads();
        buf[tid] += t;
        __syncthreads();
    }
    int excl = buf[tid] - v + blockoff;
    if (i < n) { off[i] = excl; cur[i] = excl; }
    if (i == n - 1) off[n] = n_edges;
}

__global__ __launch_bounds__(256) void fill_and_part(
    const int* __restrict__ src, const int* __restrict__ dst,
    const int* __restrict__ rel, const float* __restrict__ norm,
    int* __restrict__ cur, int2* __restrict__ emeta,
    const int* __restrict__ off, int* __restrict__ wstart, int n_edges)
{
    int t = blockIdx.x * 256 + threadIdx.x;
    if (t < n_edges) {
        int d = dst[t];
        int p = atomicAdd(&cur[d], 1);
        int2 m;
        m.x = src[t] | (rel[t] << 20);
        m.y = __float_as_int(norm[t]);
        emeta[p] = m;
    } else {
        int w = t - n_edges;
        if (w <= N_WAVES) {
            if (w == 0) {
                wstart[0] = 0;
            } else if (w == N_WAVES) {
                wstart[N_WAVES] = N_NODES;
            } else {
                int target = (int)(((long long)N_EDGES * w) / N_WAVES);
                int lo = 0, hi = N_NODES - 1;
                while (lo < hi) {
                    int mid = (lo + hi) >> 1;
                    if (off[mid + 1] > target) hi = mid; else lo = mid + 1;
                }
                wstart[w] = lo;
            }
        } else if (w <= N_WAVES + 7) {
            int2 z; z.x = 0; z.y = 0;
            emeta[n_edges + (w - N_WAVES - 1)] = z;   // 7 zero pads
        }
    }
}

// ---------------------------------------------------------------------------
// Hot kernel v12 (R25 proven best): fp16 table in LDS, persistent 256 blocks,
// inner edge loop `#pragma unroll 4`.
// Per edge: 1 meta + 1 uint4 h16 load + 2 ds_read_b128 + 8 fdot2 + 2 fma.
// ---------------------------------------------------------------------------
__global__ __launch_bounds__(1024, 4) void gather_nodes12(
    const uint4* __restrict__ h16_4, const uint32_t* __restrict__ wsw,
    const int* __restrict__ off, const int2* __restrict__ emeta,
    const int* __restrict__ wstart, float* __restrict__ out)
{
    __shared__ uint32_t wlds[NUM_RELS * 512];   // 128 KB
    {
        uint4* l4 = reinterpret_cast<uint4*>(wlds);
        const uint4* g4 = reinterpret_cast<const uint4*>(wsw);
        int t = threadIdx.x;
#pragma unroll
        for (int k = 0; k < 8; ++k)
            l4[t + k * 1024] = g4[t + k * 1024];
    }
    __syncthreads();

    const int lane = threadIdx.x & 63;
    const int wid  = threadIdx.x >> 6;
    const int b = lane >> 2;
    const int q = lane & 3;
    const uint32_t lbase = (uint32_t)(lane * 4);

    for (int wv = blockIdx.x * 16 + wid; wv < N_WAVES; wv += GATHER_B * 16) {
        const int n0 = wstart[wv];
        const int n1 = wstart[wv + 1];
        if (n0 >= n1) continue;

        int j = off[n0];
        int e_next = off[n0 + 1];

        int2 m0 = emeta[j];
        int2 m1 = emeta[j + 1];
        int2 m2 = emeta[j + 2];
        uint4 hv0 = h16_4[((uint32_t)m0.x & 0xFFFFFu) * 16 + b];
        uint4 hv1 = h16_4[((uint32_t)m1.x & 0xFFFFFu) * 16 + b];

        uint32_t base0 = ((uint32_t)m0.x >> 20) * 512 + lbase;
        uint4 wa = *reinterpret_cast<const uint4*>(&wlds[base0]);
        uint4 wb = *reinterpret_cast<const uint4*>(&wlds[base0 + 256]);

        for (int d = n0; d < n1; ++d) {
            const int idx2 = (d + 2 < n1) ? d + 2 : n1;
            const int e_nn = off[idx2];
            float a0 = 0.f, a1 = 0.f;

#pragma unroll 4
            while (j < e_next) {
                int2 m3 = emeta[j + 3];
                uint4 hv2 = h16_4[((uint32_t)m2.x & 0xFFFFFu) * 16 + b];
                uint32_t bn = ((uint32_t)m1.x >> 20) * 512 + lbase;
                uint4 wna = *reinterpret_cast<const uint4*>(&wlds[bn]);
                uint4 wnb = *reinterpret_cast<const uint4*>(&wlds[bn + 256]);

                float s0 = dot2f(hv0.x, wa.x, 0.f);
                s0 = dot2f(hv0.y, wa.y, s0);
                s0 = dot2f(hv0.z, wa.z, s0);
                s0 = dot2f(hv0.w, wa.w, s0);
                float s1 = dot2f(hv0.x, wb.x, 0.f);
                s1 = dot2f(hv0.y, wb.y, s1);
                s1 = dot2f(hv0.z, wb.z, s1);
                s1 = dot2f(hv0.w, wb.w, s1);

                const float nm = __int_as_float(m0.y);
                a0 = fmaf(s0, nm, a0);
                a1 = fmaf(s1, nm, a1);

                m0 = m1; m1 = m2; m2 = m3;
                hv0 = hv1; hv1 = hv2;
                wa = wna; wb = wnb;
                ++j;
            }

            float2* op = reinterpret_cast<float2*>(out + (size_t)d * OUT_F + b * 8 + 2 * q);
            float2 bse = *op;
            float2 res;
            res.x = fmaxf(bse.x + a0, 0.f);
            res.y = fmaxf(bse.y + a1, 0.f);
            *op = res;

            e_next = e_nn;
        }
    }
}

// ---------------------------------------------------------------------------
// Fallback hot kernel (h in f32) if ws_size can't hold h16. Same w layout.
// ---------------------------------------------------------------------------
__global__ __launch_bounds__(1024, 4) void gather_nodes6(
    const float* __restrict__ h, const uint32_t* __restrict__ wsw,
    const int* __restrict__ off, const int2* __restrict__ emeta,
    const int* __restrict__ wstart, float* __restrict__ out)
{
    __shared__ uint32_t wlds[NUM_RELS * 512];   // 128 KB
    {
        uint4* l4 = reinterpret_cast<uint4*>(wlds);
        const uint4* g4 = reinterpret_cast<const uint4*>(wsw);
        int t = threadIdx.x;
#pragma unroll
        for (int k = 0; k < 8; ++k)
            l4[t + k * 1024] = g4[t + k * 1024];
    }
    __syncthreads();

    const int lane = threadIdx.x & 63;
    const int wid  = threadIdx.x >> 6;
    const int b = lane >> 2;
    const int q = lane & 3;
    const uint32_t lbase = (uint32_t)(lane * 4);

    for (int wv = blockIdx.x * 16 + wid; wv < N_WAVES; wv += GATHER_B * 16) {
        const int n0 = wstart[wv];
        const int n1 = wstart[wv + 1];
        if (n0 >= n1) continue;

        int j = off[n0];
        int2 m0 = emeta[j];
        int2 m1 = emeta[j + 1];
        int2 m2 = emeta[j + 2];

        const float4* hr0 = reinterpret_cast<const float4*>(
            h + (size_t)((uint32_t)m0.x & 0xFFFFFu) * IN_F + b * 8);
        float4 h0A = hr0[0], h0B = hr0[1];
        const float4* hr1 = reinterpret_cast<const float4*>(
            h + (size_t)((uint32_t)m1.x & 0xFFFFFu) * IN_F + b * 8);
        float4 h1A = hr1[0], h1B = hr1[1];

        uint32_t base0 = ((uint32_t)m0.x >> 20) * 512 + lbase;
        uint4 wa = *reinterpret_cast<const uint4*>(&wlds[base0]);
        uint4 wb = *reinterpret_cast<const uint4*>(&wlds[base0 + 256]);

        for (int d = n0; d < n1; ++d) {
            const int end_d = off[d + 1];
            float a0 = 0.f, a1 = 0.f;

            while (j < end_d) {
                int2 m3 = emeta[j + 3];
                const float4* hr2 = reinterpret_cast<const float4*>(
                    h + (size_t)((uint32_t)m2.x & 0xFFFFFu) * IN_F + b * 8);
                float4 h2A = hr2[0], h2B = hr2[1];
                uint32_t bn = ((uint32_t)m1.x >> 20) * 512 + lbase;
                uint4 wna = *reinterpret_cast<const uint4*>(&wlds[bn]);
                uint4 wnb = *reinterpret_cast<const uint4*>(&wlds[bn + 256]);

                uint32_t h01 = __builtin_bit_cast(uint32_t, __builtin_amdgcn_cvt_pkrtz(h0A.x, h0A.y));
                uint32_t h23 = __builtin_bit_cast(uint32_t, __builtin_amdgcn_cvt_pkrtz(h0A.z, h0A.w));
                uint32_t h45 = __builtin_bit_cast(uint32_t, __builtin_amdgcn_cvt_pkrtz(h0B.x, h0B.y));
                uint32_t h67 = __builtin_bit_cast(uint32_t, __builtin_amdgcn_cvt_pkrtz(h0B.z, h0B.w));

                float s0 = dot2f(h01, wa.x, 0.f);
                s0 = dot2f(h23, wa.y, s0);
                s0 = dot2f(h45, wa.z, s0);
                s0 = dot2f(h67, wa.w, s0);
                float s1 = dot2f(h01, wb.x, 0.f);
                s1 = dot2f(h23, wb.y, s1);
                s1 = dot2f(h45, wb.z, s1);
                s1 = dot2f(h67, wb.w, s1);

                const float nm = __int_as_float(m0.y);
                a0 = fmaf(s0, nm, a0);
                a1 = fmaf(s1, nm, a1);

                m0 = m1; m1 = m2; m2 = m3;
                h0A = h1A; h0B = h1B; h1A = h2A; h1B = h2B;
                wa = wna; wb = wnb;
                ++j;
            }

            float2* op = reinterpret_cast<float2*>(out + (size_t)d * OUT_F + b * 8 + 2 * q);
            float2 bse = *op;
            float2 res;
            res.x = fmaxf(bse.x + a0, 0.f);
            res.y = fmaxf(bse.y + a1, 0.f);
            *op = res;
        }
    }
}

extern "C" void kernel_launch(void* const* d_in, const int* in_sizes, int n_in,
                              void* d_out, int out_size, void* d_ws, size_t ws_size,
                              hipStream_t stream)
{
    const float* h      = (const float*)d_in[0];
    const float* norm   = (const float*)d_in[1];
    const float* weight = (const float*)d_in[2];
    const float* loop_w = (const float*)d_in[3];
    const float* bias   = (const float*)d_in[4];
    const int*   src    = (const int*)d_in[5];
    const int*   dst    = (const int*)d_in[6];
    const int*   rel    = (const int*)d_in[7];
    float* out = (float*)d_out;

    // ws layout: cnt[N], off[N+1], cur[N], part[512], wstart[N_WAVES+1],
    // wsw[64*512 u32], emeta[E+7] int2, h16[N*IN_F] fp16  -> ~35 MB
    char* wsb = (char*)d_ws;
    char* ws0 = wsb;
    int*  cnt    = (int*)wsb;  wsb += sizeof(int) * N_NODES;
    int*  off    = (int*)wsb;  wsb += sizeof(int) * (N_NODES + 1);
    int*  cur    = (int*)wsb;  wsb += sizeof(int) * N_NODES;
    int*  part   = (int*)wsb;  wsb += sizeof(int) * 512;
    int*  wstart = (int*)wsb;  wsb += sizeof(int) * (N_WAVES + 1);
    wsb = (char*)(((uintptr_t)wsb + 15) & ~(uintptr_t)15);
    uint32_t* wsw = (uint32_t*)wsb; wsb += sizeof(uint32_t) * NUM_RELS * 512;
    int2* emeta = (int2*)wsb;  wsb += sizeof(int2) * (N_EDGES + 7);
    wsb = (char*)(((uintptr_t)wsb + 15) & ~(uintptr_t)15);
    uint4* h16_4 = (uint4*)wsb; wsb += (size_t)N_NODES * IN_F * 2;

    const int use_h16 = (size_t)(wsb - ws0) <= ws_size;   // host-constant

    hipMemsetAsync(cnt, 0, sizeof(int) * N_NODES, stream);

    const int h16_threads = use_h16 ? H16_ITEMS : 0;
    const int prep_blocks = (NUM_RELS * 512 + N_EDGES + h16_threads + 255) / 256;
    prep_gemm_fused<<<GEMM_B + prep_blocks, 256, 0, stream>>>(
        h, loop_w, bias, out, weight, wsw, dst, cnt, h16_4, N_EDGES, use_h16);
    block_sums<<<NB_SCAN, 256, 0, stream>>>(cnt, part, N_NODES);
    write_off2<<<NB_SCAN, 256, 0, stream>>>(cnt, part, off, cur, N_NODES, N_EDGES);
    const int fp_grid = (N_EDGES + N_WAVES + 8 + 255) / 256;
    fill_and_part<<<fp_grid, 256, 0, stream>>>(src, dst, rel, norm, cur, emeta,
                                               off, wstart, N_EDGES);

    if (use_h16) {
        gather_nodes12<<<GATHER_B, 1024, 0, stream>>>(h16_4, wsw, off, emeta, wstart, out);
    } else {
        gather_nodes6<<<GATHER_B, 1024, 0, stream>>>(h, wsw, off, emeta, wstart, out);
    }
}